// Round 7
// baseline (603.698 us; speedup 1.0000x reference)
//
#include <hip/hip_runtime.h>
#include <math.h>

// CTC loss, T=1024 B=64 V=256 L=256 (S=513).
// Round 13: FUSED single-kernel producer/consumer with cross-block flags.
// Round-12 post-mortem: ctc_rec's VGPR_Count=72 proved the 16-deep register
// ring never register-allocated (__launch_bounds__(64) capped regs; compiler
// sank ring loads to point-of-use -> ~244 cyc/step latency-serial). Also the
// two passes serialized behind ~80us fixed overhead. This round:
//  - __launch_bounds__(256,1): ~512-VGPR budget, ring stays resident.
//  - ONE kernel: blocks 0..255 = gather (1024 waves, EXACT same lse
//    partition/arithmetic -> partial[] bit-identical), blocks 256..319 = rec
//    (1 wave each). Producers release-signal rdy[b][j] after each 4 of their
//    rows (= 64-row block j); consumer acquire-spins before ISSUING loads
//    into block j (gates at windows wv%4==2, covering blank reach 16w+47).
//    Producers write partial[w] BEFORE their final signal, so gate(15)
//    also orders partial[] reads. Flags zeroed by hipMemsetAsync each launch.
//  - Producers use 2-deep row prefetch (pure load reorder, no FP change).
// All FP ops/order bit-identical to round-12's PASSING kernels.
// Fallback (shape mismatch / small ws): round-10 ctc_main+ctc_final verbatim.

constexpr int V = 256;
constexpr float LN2_F = 0.6931471805599453f;

typedef unsigned uint2v __attribute__((ext_vector_type(2)));

template <int CTRL>
__device__ __forceinline__ float dpp_mov_f(float x) {
    return __int_as_float(__builtin_amdgcn_update_dpp(
        0, __float_as_int(x), CTRL, 0xF, 0xF, true));
}

// whole-wave shift down by 1 lane (lane l reads lane l-1; lane 0 -> 0). VALU.
__device__ __forceinline__ float wave_shr1_f(float x) {
    return __int_as_float(__builtin_amdgcn_update_dpp(
        0, __float_as_int(x), 0x138, 0xF, 0xF, true));  // wave_shr:1
}

__device__ __forceinline__ float wave_max_f(float m) {
    m = fmaxf(m, dpp_mov_f<0xB1>(m));    // quad_perm xor1
    m = fmaxf(m, dpp_mov_f<0x4E>(m));    // quad_perm xor2
    m = fmaxf(m, dpp_mov_f<0x124>(m));   // row_ror:4
    m = fmaxf(m, dpp_mov_f<0x128>(m));   // row_ror:8
#if __has_builtin(__builtin_amdgcn_permlane16_swap) && __has_builtin(__builtin_amdgcn_permlane32_swap)
    uint2v a = __builtin_amdgcn_permlane16_swap(__float_as_uint(m),
                                                __float_as_uint(m), false, false);
    m = fmaxf(__uint_as_float(a.x), __uint_as_float(a.y));
    uint2v b = __builtin_amdgcn_permlane32_swap(__float_as_uint(m),
                                                __float_as_uint(m), false, false);
    m = fmaxf(__uint_as_float(b.x), __uint_as_float(b.y));
#else
    m = fmaxf(m, __shfl_xor(m, 16, 64));
    m = fmaxf(m, __shfl_xor(m, 32, 64));
#endif
    return m;
}

__device__ __forceinline__ float wave_sum_f(float s) {
    s += dpp_mov_f<0xB1>(s);
    s += dpp_mov_f<0x4E>(s);
    s += dpp_mov_f<0x124>(s);
    s += dpp_mov_f<0x128>(s);
#if __has_builtin(__builtin_amdgcn_permlane16_swap) && __has_builtin(__builtin_amdgcn_permlane32_swap)
    uint2v a = __builtin_amdgcn_permlane16_swap(__float_as_uint(s),
                                                __float_as_uint(s), false, false);
    s = __uint_as_float(a.x) + __uint_as_float(a.y);
    uint2v b = __builtin_amdgcn_permlane32_swap(__float_as_uint(s),
                                                __float_as_uint(s), false, false);
    s = __uint_as_float(b.x) + __uint_as_float(b.y);
#else
    s += __shfl_xor(s, 16, 64);
    s += __shfl_xor(s, 32, 64);
#endif
    return s;
}

#define MACS(EB, E1, E3, E5, E7) do {                                  \
    const float c7m = wave_shr1_f(cur7);                               \
    curT = (curT + cur7) * (EB);                                       \
    cur7 = fmaf(sk7, cur5, cur7 + cur6) * (E7);                        \
    cur6 = (cur6 + cur5) * (EB);                                       \
    cur5 = fmaf(sk5, cur3, cur5 + cur4) * (E5);                        \
    cur4 = (cur4 + cur3) * (EB);                                       \
    cur3 = fmaf(sk3, cur1, cur3 + cur2) * (E3);                        \
    cur2 = (cur2 + cur1) * (EB);                                       \
    cur1 = fmaf(sk1, c7m, cur1 + cur0) * (E1);                         \
    cur0 = (cur0 + c7m) * (EB);                                        \
  } while (0)

#define RENORM do {                                                    \
    curT *= mkT; cur0 *= mk0; cur1 *= mk1; cur2 *= mk2; cur3 *= mk3;   \
    cur4 *= mk4; cur5 *= mk5; cur6 *= mk6; cur7 *= mk7;                \
    float _m = fmaxf(curT, cur0); _m = fmaxf(_m, cur1);                \
    _m = fmaxf(_m, cur2); _m = fmaxf(_m, cur3); _m = fmaxf(_m, cur4);  \
    _m = fmaxf(_m, cur5); _m = fmaxf(_m, cur6); _m = fmaxf(_m, cur7);  \
    _m = wave_max_f(_m);                                               \
    const float _inv = 1.f / fmaxf(_m, 1e-30f);                        \
    log2acc -= log2f(_inv);                                            \
    curT *= _inv; cur0 *= _inv; cur1 *= _inv; cur2 *= _inv;            \
    cur3 *= _inv; cur4 *= _inv; cur5 *= _inv; cur6 *= _inv;            \
    cur7 *= _inv;                                                      \
  } while (0)

// ----- consumer macros (expect gb, bb_, Tm1, Tm4, l in scope) -----
#define GROWC(TROW) (*(const float4*)(gb + 256 * (size_t)((TROW) > Tm1 ? Tm1 : (TROW)) + 4 * l))
#define BROWC(TROW) (*(const float4*)(bb_ + ((TROW) > Tm4 ? Tm4 : (TROW))))

#define KSTEP(TT, SL, ABL) do {                                        \
    MACS((ABL), R##SL.x, R##SL.y, R##SL.z, R##SL.w);                   \
    R##SL = GROWC((TT) + 16);                                          \
  } while (0)

#define WIN16(BASE, K0, K1, K2, K3) do {                               \
    KSTEP((BASE) +  0,  0, (K0).x); KSTEP((BASE) +  1,  1, (K0).y);    \
    KSTEP((BASE) +  2,  2, (K0).z); KSTEP((BASE) +  3,  3, (K0).w);    \
    K0 = BROWC((BASE) + 32);                                           \
    KSTEP((BASE) +  4,  4, (K1).x); KSTEP((BASE) +  5,  5, (K1).y);    \
    KSTEP((BASE) +  6,  6, (K1).z); KSTEP((BASE) +  7,  7, (K1).w);    \
    K1 = BROWC((BASE) + 36);                                           \
    KSTEP((BASE) +  8,  8, (K2).x); KSTEP((BASE) +  9,  9, (K2).y);    \
    KSTEP((BASE) + 10, 10, (K2).z); KSTEP((BASE) + 11, 11, (K2).w);    \
    K2 = BROWC((BASE) + 40);                                           \
    KSTEP((BASE) + 12, 12, (K3).x); KSTEP((BASE) + 13, 13, (K3).y);    \
    KSTEP((BASE) + 14, 14, (K3).z); KSTEP((BASE) + 15, 15, (K3).w);    \
    K3 = BROWC((BASE) + 44);                                           \
    RENORM;                                                            \
  } while (0)

#define W0FIRST() do {                                                 \
    KSTEP( 1,  1, blkA0.y); KSTEP( 2,  2, blkA0.z); KSTEP( 3,  3, blkA0.w); \
    blkA0 = BROWC(32);                                                 \
    KSTEP( 4,  4, blkA1.x); KSTEP( 5,  5, blkA1.y);                    \
    KSTEP( 6,  6, blkA1.z); KSTEP( 7,  7, blkA1.w);                    \
    blkA1 = BROWC(36);                                                 \
    KSTEP( 8,  8, blkA2.x); KSTEP( 9,  9, blkA2.y);                    \
    KSTEP(10, 10, blkA2.z); KSTEP(11, 11, blkA2.w);                    \
    blkA2 = BROWC(40);                                                 \
    KSTEP(12, 12, blkA3.x); KSTEP(13, 13, blkA3.y);                    \
    KSTEP(14, 14, blkA3.z); KSTEP(15, 15, blkA3.w);                    \
    blkA3 = BROWC(44);                                                 \
    RENORM;                                                            \
  } while (0)

// acquire-spin until all 16 producer-waves of batch b have finished 64-row
// block g (each does one release fetch_add). Acquire also invalidates
// stale cache lines before this block's ggath loads are issued.
__device__ __forceinline__ void wait_blk(int* rdy, int b, int g) {
    while (__hip_atomic_load(&rdy[b * 16 + g], __ATOMIC_ACQUIRE,
                             __HIP_MEMORY_SCOPE_AGENT) < 16)
        __builtin_amdgcn_s_sleep(2);
}

// =====================================================================
// FUSED kernel. Grid = 256 gather blocks (256 thr) + 64 rec blocks.
// Host guarantees T==1024, B==64 (shape-gated).
// =====================================================================
__global__ __launch_bounds__(256, 1) void ctc_fused(
    const int*   __restrict__ labels,      // [B, L]
    const float* __restrict__ logits,      // [T, B, V]
    const int*   __restrict__ label_len,   // [B]
    const int*   __restrict__ logit_len,   // [B]
    float*       __restrict__ partial,     // [1024]
    float*       __restrict__ ggath,       // [B, T, 256]
    float*       __restrict__ bgath,       // [B, T]
    float*       __restrict__ vbuf,        // [B]
    int*                      cnt,         // [1]  (memset to 0 pre-launch)
    int*                      rdy,         // [B*16] (memset to 0 pre-launch)
    float*       __restrict__ out,         // [1]
    int T, int B, int L)
{
    const int tid = threadIdx.x;
    const int wid = tid >> 6;
    const int l   = tid & 63;

    if ((int)blockIdx.x < 256) {
        // ================= gather + lse (producer) ========================
        __shared__ __align__(16) float erow[4][256];
        float* er = erow[wid];

        const int w  = (int)blockIdx.x * 4 + wid;     // 0..1023
        const int bb = w & 63;
        const int q  = w >> 6;                        // starting t
        const int Tbb = logit_len[bb];

        const int4 lb4 = ((const int4*)(labels + (size_t)bb * L))[l];
        const int ix = lb4.x, iy = lb4.y, iz = lb4.z, iw = lb4.w;

        float acc = 0.f;
        int r = w;                                    // linear row index
        int t = q;
        // 2-deep row prefetch (pure load reordering; FP order unchanged)
        float4 n0 = ((const float4*)(logits + (size_t)r * V))[l];
        float4 n1 = ((const float4*)(logits + (size_t)(r + 1024) * V))[l];
        for (int k = 0; k < 64; ++k) {
            const float4 x = n0;
            n0 = n1;
            if (k + 2 < 64)
                n1 = ((const float4*)(logits + (size_t)(r + 2048) * V))[l];
            // exp'd row -> LDS (same ops/order as round-12 k1)
            float4 e4;
            e4.x = __expf(x.x); e4.y = __expf(x.y);
            e4.z = __expf(x.z); e4.w = __expf(x.w);
            ((float4*)er)[l] = e4;
            // lse (identical arithmetic/order -> partial[] bit-identical)
            float m = fmaxf(fmaxf(x.x, x.y), fmaxf(x.z, x.w));
            m = wave_max_f(m);
            float ss = __expf(x.x - m) + __expf(x.y - m) +
                       __expf(x.z - m) + __expf(x.w - m);
            ss = wave_sum_f(ss);
            // gather reads (same-wave DS, in-order)
            float4 g;
            g.x = er[ix]; g.y = er[iy]; g.z = er[iz]; g.w = er[iw];
            const float gb0 = er[0];
            float* gr = ggath + ((size_t)bb * T + t) * 256;
            ((float4*)gr)[l] = g;
            if (l == 0) bgath[(size_t)bb * T + t] = gb0;
            if (t < Tbb) acc += m + logf(ss);
            // release-signal 64-row block (k>>2); last block after partial
            if ((k & 3) == 3 && k != 63) {
                if (l == 0)
                    __hip_atomic_fetch_add(&rdy[bb * 16 + (k >> 2)], 1,
                                           __ATOMIC_RELEASE,
                                           __HIP_MEMORY_SCOPE_AGENT);
            }
            r += 1024; t += 16;
        }
        if (l == 0) {
            partial[w] = acc;                          // BEFORE final signal
            __hip_atomic_fetch_add(&rdy[bb * 16 + 15], 1, __ATOMIC_RELEASE,
                                   __HIP_MEMORY_SCOPE_AGENT);
        }
    } else {
        // ======================= recursion (consumer) =====================
        if (wid != 0) return;                          // 1 wave per rec block
        const int b = (int)blockIdx.x - 256;
        __shared__ float afin[514];

        const int Tb = logit_len[b];
        const int Lb = label_len[b];
        const int Sb = 2 * Lb + 1;
        const int Tm1 = T - 1;
        const int Tm4 = T - 4;

        const float* lg  = logits + (size_t)b * V;
        const size_t rs  = (size_t)B * V;
        const float* gb  = ggath + (size_t)b * T * 256;
        const float* bb_ = bgath + (size_t)b * T;

        const int4 lb4 = ((const int4*)(labels + (size_t)b * L))[l];
        const int ix = lb4.x, iy = lb4.y, iz = lb4.z, iw = lb4.w;
        const int prevw = __shfl_up(iw, 1);
        const float sk1 = (l > 0 && ix != prevw) ? 1.f : 0.f;
        const float sk3 = (iy != ix) ? 1.f : 0.f;
        const float sk5 = (iz != iy) ? 1.f : 0.f;
        const float sk7 = (iw != iz) ? 1.f : 0.f;

        const float mk0 = (8 * l + 0 < Sb) ? 1.f : 0.f;
        const float mk1 = (8 * l + 1 < Sb) ? 1.f : 0.f;
        const float mk2 = (8 * l + 2 < Sb) ? 1.f : 0.f;
        const float mk3 = (8 * l + 3 < Sb) ? 1.f : 0.f;
        const float mk4 = (8 * l + 4 < Sb) ? 1.f : 0.f;
        const float mk5 = (8 * l + 5 < Sb) ? 1.f : 0.f;
        const float mk6 = (8 * l + 6 < Sb) ? 1.f : 0.f;
        const float mk7 = (8 * l + 7 < Sb) ? 1.f : 0.f;
        const float mkT = (Sb > 512 && l == 63) ? 1.f : 0.f;

        float cur0 = 0.f, cur1 = 0.f, cur2 = 0.f, cur3 = 0.f;
        float cur4 = 0.f, cur5 = 0.f, cur6 = 0.f, cur7 = 0.f, curT = 0.f;
        if (l == 0) {
            cur0 = __expf(lg[0]);
            cur1 = __expf(lg[ix]) * mk1;
        }
        float log2acc = 0.f;

        int base = 1;
        if (Tb >= 16) {
            wait_blk(rdy, b, 0);               // rows 0..63 ready
            float4 R0, R1, R2, R3, R4, R5, R6, R7;
            float4 R8, R9, R10, R11, R12, R13, R14, R15;
            R1  = GROWC(1);  R2  = GROWC(2);  R3  = GROWC(3);  R4  = GROWC(4);
            R5  = GROWC(5);  R6  = GROWC(6);  R7  = GROWC(7);  R8  = GROWC(8);
            R9  = GROWC(9);  R10 = GROWC(10); R11 = GROWC(11); R12 = GROWC(12);
            R13 = GROWC(13); R14 = GROWC(14); R15 = GROWC(15); R0  = GROWC(16);
            float4 blkA0 = BROWC(0),  blkA1 = BROWC(4);
            float4 blkA2 = BROWC(8),  blkA3 = BROWC(12);
            float4 blkB0 = BROWC(16), blkB1 = BROWC(20);
            float4 blkB2 = BROWC(24), blkB3 = BROWC(28);

            W0FIRST();                         // t=1..15 (touches <= row 47)
            int wv = 1;
            for (base = 16; base + 16 <= Tb; base += 16, ++wv) {
                if ((wv & 3) == 2) {           // window wv touches block g
                    const int g = (wv + 2) >> 2;
                    if (g < 16) wait_blk(rdy, b, g);
                }
                if (wv & 1) WIN16(base, blkB0, blkB1, blkB2, blkB3);
                else        WIN16(base, blkA0, blkA1, blkA2, blkA3);
            }
        }
        // scalar tail (raw logits, identical numerics)
        for (int t = base; t < Tb; ++t) {
            const float* rowp = lg + rs * (size_t)t;
            const float eb = __expf(rowp[0]);
            const float e1 = __expf(rowp[ix]), e3 = __expf(rowp[iy]);
            const float e5 = __expf(rowp[iz]), e7 = __expf(rowp[iw]);
            MACS(eb, e1, e3, e5, e7);
        }

        // readout
        afin[8 * l + 0] = cur0; afin[8 * l + 1] = cur1;
        afin[8 * l + 2] = cur2; afin[8 * l + 3] = cur3;
        afin[8 * l + 4] = cur4; afin[8 * l + 5] = cur5;
        afin[8 * l + 6] = cur6; afin[8 * l + 7] = cur7;
        if (l == 63) afin[512] = curT;
        const int end = 2 * Lb;
        const int em1 = (end > 0) ? end - 1 : 0;
        float ssum = afin[end] + afin[em1];
        ssum = fmaxf(ssum, 1e-37f);
        const float lnt = logf(ssum) + LN2_F * log2acc;

        // ensure ALL producers of b finished (covers Tb<T paths too);
        // gate(15) also orders their partial[] writes.
        for (int g = 0; g < 16; ++g) wait_blk(rdy, b, g);

        float c = 0.f;
        for (int k = b; k < 1024; k += 64) c += partial[k];
        const float v = c - lnt;

        int old = 0;
        if (l == 0) {
            atomicExch(&vbuf[b], v);
            __threadfence();
            old = atomicAdd(cnt, 1);
        }
        old = __shfl(old, 0, 64);
        if (old == B - 1) {                    // last rec block: final mean
            __threadfence();
            float vv = atomicAdd(&vbuf[l], 0.0f);
            #pragma unroll
            for (int o = 32; o >= 1; o >>= 1) vv += __shfl_xor(vv, o, 64);
            if (l == 0) out[0] = vv / (float)B;
        }
    }
}

// =====================================================================
// FALLBACK PATH (round-10 kernels, verbatim): shape mismatch / small ws
// =====================================================================
#define PRE(N, S) do {                                                 \
    G##N = *(const float4*)(&gbuf[h][S][l][0]);                        \
    A##N = bbuf[h][S];                                                 \
  } while (0)
#define STEPR(N, S) do {                                               \
    MACS(A##N, G##N.x, G##N.y, G##N.z, G##N.w);                        \
    PRE(N, S);                                                         \
  } while (0)
#define STEPC(N) MACS(A##N, G##N.x, G##N.y, G##N.z, G##N.w)

#define PLOAD(dst, WV, J)                                              \
    dst = *(const float4*)(lg + rs * (size_t)(16 * (WV) + p + 7 * (J)) + 4 * l)
#define PROC(XV, i) do {                                               \
    float4 _e;                                                         \
    _e.x = __expf((XV).x); _e.y = __expf((XV).y);                      \
    _e.z = __expf((XV).z); _e.w = __expf((XV).w);                      \
    *(float4*)&prow[p][4 * l] = _e;                                    \
    const float* _pr = prow[p];                                        \
    float _gb = _pr[0];                                                \
    float4 _gv;                                                        \
    _gv.x = _pr[ix]; _gv.y = _pr[iy]; _gv.z = _pr[iz]; _gv.w = _pr[iw];\
    *(float4*)&gbuf[h][i][l][0] = _gv;                                 \
    if (l == 0) bbuf[h][i] = _gb;                                      \
  } while (0)

#define WG_BARRIER asm volatile("s_waitcnt lgkmcnt(0)\n\ts_barrier" ::: "memory")

__global__ __launch_bounds__(512) void ctc_main(
    const int*   __restrict__ labels,
    const float* __restrict__ logits,
    const int*   __restrict__ label_len,
    const int*   __restrict__ logit_len,
    float*       __restrict__ partial,
    float*       __restrict__ lnterm,
    int T, int B, int L)
{
    const int tid = threadIdx.x;
    const int wid = tid >> 6;
    const int l   = tid & 63;

    if ((int)blockIdx.x < B) {
        __shared__ __align__(16) float gbuf[2][16][64][4];
        __shared__ float bbuf[2][16];
        __shared__ __align__(16) float prow[7][256];
        __shared__ float afin[514];

        const int b = blockIdx.x;
        const int Tb = logit_len[b];
        const int Lb = label_len[b];
        const int Sb = 2 * Lb + 1;

        const float* lg = logits + (size_t)b * V;
        const size_t rs = (size_t)B * V;

        const int4 lb4 = ((const int4*)(labels + (size_t)b * L))[l];
        const int ix = lb4.x, iy = lb4.y, iz = lb4.z, iw = lb4.w;
        const int prevw = __shfl_up(iw, 1);
        const float sk1 = (l > 0 && ix != prevw) ? 1.f : 0.f;
        const float sk3 = (iy != ix) ? 1.f : 0.f;
        const float sk5 = (iz != iy) ? 1.f : 0.f;
        const float sk7 = (iw != iz) ? 1.f : 0.f;

        const float mk0 = (8 * l + 0 < Sb) ? 1.f : 0.f;
        const float mk1 = (8 * l + 1 < Sb) ? 1.f : 0.f;
        const float mk2 = (8 * l + 2 < Sb) ? 1.f : 0.f;
        const float mk3 = (8 * l + 3 < Sb) ? 1.f : 0.f;
        const float mk4 = (8 * l + 4 < Sb) ? 1.f : 0.f;
        const float mk5 = (8 * l + 5 < Sb) ? 1.f : 0.f;
        const float mk6 = (8 * l + 6 < Sb) ? 1.f : 0.f;
        const float mk7 = (8 * l + 7 < Sb) ? 1.f : 0.f;
        const float mkT = (Sb > 512 && l == 63) ? 1.f : 0.f;

        float cur0 = 0.f, cur1 = 0.f, cur2 = 0.f, cur3 = 0.f;
        float cur4 = 0.f, cur5 = 0.f, cur6 = 0.f, cur7 = 0.f, curT = 0.f;
        if (l == 0) {
            cur0 = __expf(lg[0]);
            cur1 = __expf(lg[ix]) * mk1;
        }
        float log2acc = 0.f;

        const int NW = Tb / 16;

        float4 G0{}, G1{}, G2{}, G3{}, G4{}, G5{}, G6{}, G7{};
        float  A0 = 0, A1 = 0, A2 = 0, A3 = 0, A4 = 0, A5 = 0, A6 = 0, A7 = 0;

        const int p = (wid > 0) ? wid - 1 : 0;
        const bool three = (p < 2);
        float4 ca{}, cb{}, cc{}, na{}, nb{}, nc{};
        if (wid > 0 && NW > 0) {
            PLOAD(ca, 0, 0);
            PLOAD(cb, 0, 1);
            if (three) PLOAD(cc, 0, 2);
        }
        if (wid == 0) __builtin_amdgcn_s_setprio(1);

        for (int k = 0; k <= NW; ++k) {
            if (wid != 0) {
                if (k < NW) {
                    const int h = k & 1;
                    if (k + 1 < NW) {
                        PLOAD(na, k + 1, 0);
                        PLOAD(nb, k + 1, 1);
                        if (three) PLOAD(nc, k + 1, 2);
                    }
                    PROC(ca, p);
                    PROC(cb, p + 7);
                    if (three) PROC(cc, p + 14);
                    ca = na; cb = nb; cc = nc;
                }
            } else if (k >= 1) {
                const int w = k - 1;
                const int h = w & 1;
                if (w == 0) {
                    PRE(1, 1); PRE(2, 2); PRE(3, 3); PRE(4, 4);
                    PRE(5, 5); PRE(6, 6); PRE(7, 7); PRE(0, 8);
                    STEPR(1, 9);  STEPR(2, 10); STEPR(3, 11); STEPR(4, 12);
                    STEPR(5, 13); STEPR(6, 14); STEPR(7, 15);
                    STEPC(0);
                    STEPC(1); STEPC(2); STEPC(3); STEPC(4);
                    STEPC(5); STEPC(6); STEPC(7);
                } else {
                    PRE(0, 0); PRE(1, 1); PRE(2, 2); PRE(3, 3);
                    PRE(4, 4); PRE(5, 5); PRE(6, 6); PRE(7, 7);
                    STEPR(0, 8);  STEPR(1, 9);  STEPR(2, 10); STEPR(3, 11);
                    STEPR(4, 12); STEPR(5, 13); STEPR(6, 14); STEPR(7, 15);
                    STEPC(0); STEPC(1); STEPC(2); STEPC(3);
                    STEPC(4); STEPC(5); STEPC(6); STEPC(7);
                }
                RENORM;
            }
            WG_BARRIER;
        }

        if (wid == 0) {
            for (int t = 16 * NW; t < Tb; ++t) {
                if (t < 1) continue;
                const float* rowp = lg + rs * (size_t)t;
                const float eb = __expf(rowp[0]);
                const float e1 = __expf(rowp[ix]), e3 = __expf(rowp[iy]);
                const float e5 = __expf(rowp[iz]), e7 = __expf(rowp[iw]);
                MACS(eb, e1, e3, e5, e7);
            }

            afin[8 * l + 0] = cur0; afin[8 * l + 1] = cur1;
            afin[8 * l + 2] = cur2; afin[8 * l + 3] = cur3;
            afin[8 * l + 4] = cur4; afin[8 * l + 5] = cur5;
            afin[8 * l + 6] = cur6; afin[8 * l + 7] = cur7;
            if (l == 63) afin[512] = curT;
            const int end = 2 * Lb;
            const int em1 = (end > 0) ? end - 1 : 0;
            float ssum = afin[end] + afin[em1];
            ssum = fmaxf(ssum, 1e-37f);
            if (l == 0) lnterm[b] = logf(ssum) + LN2_F * log2acc;
        }
    } else {
        const int w  = ((int)blockIdx.x - B) * 8 + wid;
        const int nW = ((int)gridDim.x - B) * 8;
        const int rows = T * B;
        const int bb = w % B;
        const int Tbb = logit_len[bb];
        float acc = 0.f;
        int r = w;
        if (r < rows) {
            int t = w / B;
            const int ts = nW / B;
            float4 nxt = ((const float4*)(logits + (size_t)r * V))[l];
            while (true) {
                const int rn = r + nW;
                const bool more = rn < rows;
                const float4 x = nxt;
                if (more) nxt = ((const float4*)(logits + (size_t)rn * V))[l];
                float m = fmaxf(fmaxf(x.x, x.y), fmaxf(x.z, x.w));
                m = wave_max_f(m);
                float ss = __expf(x.x - m) + __expf(x.y - m) +
                           __expf(x.z - m) + __expf(x.w - m);
                ss = wave_sum_f(ss);
                if (t < Tbb) acc += m + logf(ss);
                if (!more) break;
                r = rn; t += ts;
            }
        }
        if (l == 0) partial[w] = acc;
    }
}

__global__ __launch_bounds__(64) void ctc_final(
    const float* __restrict__ partial,
    const float* __restrict__ lnterm,
    float* __restrict__ out, int B, int nW)
{
    const int b = threadIdx.x;
    float v = 0.f;
    if (b < B) {
        float c = 0.f;
        for (int k = b; k < nW; k += B) c += partial[k];
        v = c - lnterm[b];
    }
    #pragma unroll
    for (int o = 32; o >= 1; o >>= 1) v += __shfl_xor(v, o, 64);
    if (threadIdx.x == 0) out[0] = v / (float)B;
}

extern "C" void kernel_launch(void* const* d_in, const int* in_sizes, int n_in,
                              void* d_out, int out_size, void* d_ws, size_t ws_size,
                              hipStream_t stream) {
    const int*   labels    = (const int*)d_in[0];
    const float* labels_f  = nullptr; (void)labels_f;
    const float* logits    = (const float*)d_in[1];
    const int*   label_len = (const int*)d_in[2];
    const int*   logit_len = (const int*)d_in[3];

    const int B = in_sizes[2];                 // 64
    const int L = in_sizes[0] / B;             // 256
    const int T = in_sizes[1] / (B * V);       // 1024

    const int nLse = 1024;

    const size_t ggathN = (size_t)B * T * 256;       // floats
    const size_t bgathN = (size_t)B * T;             // floats
    const size_t needF  = (ggathN + bgathN + nLse + B) * sizeof(float)
                        + (size_t)(1 + 1024) * sizeof(int) + 256;

    if (T == 1024 && B == 64 && ws_size >= needF) {
        float* ggath   = (float*)d_ws;
        float* bgath   = ggath + ggathN;
        float* partial = bgath + bgathN;
        float* vbuf    = partial + nLse;
        int*   cnt     = (int*)(vbuf + B);
        int*   rdy     = cnt + 1;

        // zero flags + arrival counter (stream-ordered; graph-capture safe)
        hipMemsetAsync(cnt, 0, (size_t)(1 + 1024) * sizeof(int), stream);

        ctc_fused<<<256 + 64, 256, 0, stream>>>(labels, logits, label_len,
                                                logit_len, partial, ggath,
                                                bgath, vbuf, cnt, rdy,
                                                (float*)d_out, T, B, L);
    } else {
        // fallback: round-10 path
        float* partial = (float*)d_ws;             // [nLse]
        float* lnterm  = partial + nLse;           // [B]
        ctc_main<<<B + nLse / 8, 512, 0, stream>>>(labels, logits, label_len,
                                                   logit_len, partial, lnterm,
                                                   T, B, L);
        ctc_final<<<1, 64, 0, stream>>>(partial, lnterm, (float*)d_out, B, nLse);
    }
}

// Round 8
// 174.444 us; speedup vs baseline: 3.4607x; 3.4607x over previous
//
#include <hip/hip_runtime.h>
#include <math.h>

// CTC loss, T=1024 B=64 V=256 L=256 (S=513).
// Round 14: back to round-4's PROVEN LDS-window producer/consumer (78 µs),
// with the two measured producer-side costs removed:
//  (a) producers are now WRITE-ONLY: load row (2-window reg prefetch),
//      4 exps, one ds_write_b128 into erow[half][slot]. No LDS reads, no
//      lgkm round-trips, no gbuf. The scattered label-gathers move to the
//      consumer's PRE (5 ds_read_b32), whose 7-step ring slack hides them.
//  (b) lse is FOLDED INTO the producers: producer slot s handles exactly the
//      rows of old lse wave (b, q=s) in the same ascending order with the
//      same DPP/permlane reduce ops -> per-wave acc bit-identical. The 1024
//      separate lse waves are gone; partial[] becomes accbuf[16] in LDS,
//      summed by the consumer in the old ctc_final order.
// Block = 1024 thr (16 waves): wave0 consumer, waves1..15 producers (wave15
// takes slots 14 and 15). Grid = B blocks + tiny ctc_final. Consumer ring
// schedule, MACS order, renorm points (t=15,31,...), init/tail: bit-identical
// to round-4's passing kernel.
// Fallback (shape mismatch): round-4 kernels verbatim (FB_ prefix).

constexpr int V = 256;
constexpr float LN2_F = 0.6931471805599453f;

typedef unsigned uint2v __attribute__((ext_vector_type(2)));

template <int CTRL>
__device__ __forceinline__ float dpp_mov_f(float x) {
    return __int_as_float(__builtin_amdgcn_update_dpp(
        0, __float_as_int(x), CTRL, 0xF, 0xF, true));
}

// whole-wave shift down by 1 lane (lane l reads lane l-1; lane 0 -> 0). VALU.
__device__ __forceinline__ float wave_shr1_f(float x) {
    return __int_as_float(__builtin_amdgcn_update_dpp(
        0, __float_as_int(x), 0x138, 0xF, 0xF, true));  // wave_shr:1
}

__device__ __forceinline__ float wave_max_f(float m) {
    m = fmaxf(m, dpp_mov_f<0xB1>(m));    // quad_perm xor1
    m = fmaxf(m, dpp_mov_f<0x4E>(m));    // quad_perm xor2
    m = fmaxf(m, dpp_mov_f<0x124>(m));   // row_ror:4
    m = fmaxf(m, dpp_mov_f<0x128>(m));   // row_ror:8
#if __has_builtin(__builtin_amdgcn_permlane16_swap) && __has_builtin(__builtin_amdgcn_permlane32_swap)
    uint2v a = __builtin_amdgcn_permlane16_swap(__float_as_uint(m),
                                                __float_as_uint(m), false, false);
    m = fmaxf(__uint_as_float(a.x), __uint_as_float(a.y));
    uint2v b = __builtin_amdgcn_permlane32_swap(__float_as_uint(m),
                                                __float_as_uint(m), false, false);
    m = fmaxf(__uint_as_float(b.x), __uint_as_float(b.y));
#else
    m = fmaxf(m, __shfl_xor(m, 16, 64));
    m = fmaxf(m, __shfl_xor(m, 32, 64));
#endif
    return m;
}

__device__ __forceinline__ float wave_sum_f(float s) {
    s += dpp_mov_f<0xB1>(s);
    s += dpp_mov_f<0x4E>(s);
    s += dpp_mov_f<0x124>(s);
    s += dpp_mov_f<0x128>(s);
#if __has_builtin(__builtin_amdgcn_permlane16_swap) && __has_builtin(__builtin_amdgcn_permlane32_swap)
    uint2v a = __builtin_amdgcn_permlane16_swap(__float_as_uint(s),
                                                __float_as_uint(s), false, false);
    s = __uint_as_float(a.x) + __uint_as_float(a.y);
    uint2v b = __builtin_amdgcn_permlane32_swap(__float_as_uint(s),
                                                __float_as_uint(s), false, false);
    s = __uint_as_float(b.x) + __uint_as_float(b.y);
#else
    s += __shfl_xor(s, 16, 64);
    s += __shfl_xor(s, 32, 64);
#endif
    return s;
}

#define MACS(EB, E1, E3, E5, E7) do {                                  \
    const float c7m = wave_shr1_f(cur7);                               \
    curT = (curT + cur7) * (EB);                                       \
    cur7 = fmaf(sk7, cur5, cur7 + cur6) * (E7);                        \
    cur6 = (cur6 + cur5) * (EB);                                       \
    cur5 = fmaf(sk5, cur3, cur5 + cur4) * (E5);                        \
    cur4 = (cur4 + cur3) * (EB);                                       \
    cur3 = fmaf(sk3, cur1, cur3 + cur2) * (E3);                        \
    cur2 = (cur2 + cur1) * (EB);                                       \
    cur1 = fmaf(sk1, c7m, cur1 + cur0) * (E1);                         \
    cur0 = (cur0 + c7m) * (EB);                                        \
  } while (0)

#define RENORM do {                                                    \
    curT *= mkT; cur0 *= mk0; cur1 *= mk1; cur2 *= mk2; cur3 *= mk3;   \
    cur4 *= mk4; cur5 *= mk5; cur6 *= mk6; cur7 *= mk7;                \
    float _m = fmaxf(curT, cur0); _m = fmaxf(_m, cur1);                \
    _m = fmaxf(_m, cur2); _m = fmaxf(_m, cur3); _m = fmaxf(_m, cur4);  \
    _m = fmaxf(_m, cur5); _m = fmaxf(_m, cur6); _m = fmaxf(_m, cur7);  \
    _m = wave_max_f(_m);                                               \
    const float _inv = 1.f / fmaxf(_m, 1e-30f);                        \
    log2acc -= log2f(_inv);                                            \
    curT *= _inv; cur0 *= _inv; cur1 *= _inv; cur2 *= _inv;            \
    cur3 *= _inv; cur4 *= _inv; cur5 *= _inv; cur6 *= _inv;            \
    cur7 *= _inv;                                                      \
  } while (0)

// consumer gather-set ring (8 sets x 5 scalars) reading exp'd rows from LDS
#define DECLSET(N) float g##N##a = 0, g##N##b = 0, g##N##c = 0,        \
                         g##N##d = 0, g##N##e = 0
#define PRE(N, S) do {                                                 \
    const float* _er = er + 256 * (S);                                 \
    g##N##a = _er[ix]; g##N##b = _er[iy];                              \
    g##N##c = _er[iz]; g##N##d = _er[iw];                              \
    g##N##e = _er[0];                                                  \
  } while (0)
#define STEPR(N, S) do {                                               \
    MACS(g##N##e, g##N##a, g##N##b, g##N##c, g##N##d);                 \
    PRE(N, S);                                                         \
  } while (0)
#define STEPC(N) MACS(g##N##e, g##N##a, g##N##b, g##N##c, g##N##d)

#define WG_BARRIER asm volatile("s_waitcnt lgkmcnt(0)\n\ts_barrier" ::: "memory")

__global__ __launch_bounds__(1024) void ctc_main(
    const int*   __restrict__ labels,      // [B, L]
    const float* __restrict__ logits,      // [T, B, V]
    const int*   __restrict__ label_len,   // [B]
    const int*   __restrict__ logit_len,   // [B]
    float*       __restrict__ vres,        // [B] per-batch (lse_sum - lnterm)
    int T, int B, int L)
{
    const int tid = threadIdx.x;
    const int wid = tid >> 6;              // wave 0 consumer, 1..15 producers
    const int l   = tid & 63;
    const int b   = blockIdx.x;

    __shared__ __align__(16) float erow[2][16][256];  // exp'd rows, dbuf
    __shared__ float afin[514];
    __shared__ float accbuf[16];                      // per-slot lse sums

    const int Tb = logit_len[b];
    const int Lb = label_len[b];
    const int NW = Tb / 16;

    const float* lg = logits + (size_t)b * V;
    const size_t rs = (size_t)B * V;

    if (wid == 0) {
        // ============================ consumer ============================
        __builtin_amdgcn_s_setprio(1);
        const int Sb = 2 * Lb + 1;

        const int4 lb4 = ((const int4*)(labels + (size_t)b * L))[l];
        const int ix = lb4.x, iy = lb4.y, iz = lb4.z, iw = lb4.w;
        const int prevw = __shfl_up(iw, 1);
        const float sk1 = (l > 0 && ix != prevw) ? 1.f : 0.f;
        const float sk3 = (iy != ix) ? 1.f : 0.f;
        const float sk5 = (iz != iy) ? 1.f : 0.f;
        const float sk7 = (iw != iz) ? 1.f : 0.f;

        const float mk0 = (8 * l + 0 < Sb) ? 1.f : 0.f;
        const float mk1 = (8 * l + 1 < Sb) ? 1.f : 0.f;
        const float mk2 = (8 * l + 2 < Sb) ? 1.f : 0.f;
        const float mk3 = (8 * l + 3 < Sb) ? 1.f : 0.f;
        const float mk4 = (8 * l + 4 < Sb) ? 1.f : 0.f;
        const float mk5 = (8 * l + 5 < Sb) ? 1.f : 0.f;
        const float mk6 = (8 * l + 6 < Sb) ? 1.f : 0.f;
        const float mk7 = (8 * l + 7 < Sb) ? 1.f : 0.f;
        const float mkT = (Sb > 512 && l == 63) ? 1.f : 0.f;

        // t=0 init (identical to round-4)
        float cur0 = 0.f, cur1 = 0.f, cur2 = 0.f, cur3 = 0.f;
        float cur4 = 0.f, cur5 = 0.f, cur6 = 0.f, cur7 = 0.f, curT = 0.f;
        if (l == 0) {
            cur0 = __expf(lg[0]);
            cur1 = __expf(lg[ix]) * mk1;
        }
        float log2acc = 0.f;

        DECLSET(0); DECLSET(1); DECLSET(2); DECLSET(3);
        DECLSET(4); DECLSET(5); DECLSET(6); DECLSET(7);

        for (int k = 0; k <= NW; ++k) {
            if (k >= 1) {
                const int w = k - 1;
                const float* er = &erow[w & 1][0][0];
                if (w == 0) {
                    PRE(1, 1); PRE(2, 2); PRE(3, 3); PRE(4, 4);
                    PRE(5, 5); PRE(6, 6); PRE(7, 7); PRE(0, 8);
                    STEPR(1, 9);  STEPR(2, 10); STEPR(3, 11); STEPR(4, 12);
                    STEPR(5, 13); STEPR(6, 14); STEPR(7, 15);
                    STEPC(0);
                    STEPC(1); STEPC(2); STEPC(3); STEPC(4);
                    STEPC(5); STEPC(6); STEPC(7);
                } else {
                    PRE(0, 0); PRE(1, 1); PRE(2, 2); PRE(3, 3);
                    PRE(4, 4); PRE(5, 5); PRE(6, 6); PRE(7, 7);
                    STEPR(0, 8);  STEPR(1, 9);  STEPR(2, 10); STEPR(3, 11);
                    STEPR(4, 12); STEPR(5, 13); STEPR(6, 14); STEPR(7, 15);
                    STEPC(0); STEPC(1); STEPC(2); STEPC(3);
                    STEPC(4); STEPC(5); STEPC(6); STEPC(7);
                }
                RENORM;
            }
            WG_BARRIER;
        }

        // scalar tail (t = 16*NW..Tb-1), raw logits, identical numerics
        for (int t = 16 * NW; t < Tb; ++t) {
            if (t < 1) continue;
            const float* rowp = lg + rs * (size_t)t;
            const float eb = __expf(rowp[0]);
            const float e1 = __expf(rowp[ix]), e3 = __expf(rowp[iy]);
            const float e5 = __expf(rowp[iz]), e7 = __expf(rowp[iw]);
            MACS(eb, e1, e3, e5, e7);
        }

        afin[8 * l + 0] = cur0; afin[8 * l + 1] = cur1;
        afin[8 * l + 2] = cur2; afin[8 * l + 3] = cur3;
        afin[8 * l + 4] = cur4; afin[8 * l + 5] = cur5;
        afin[8 * l + 6] = cur6; afin[8 * l + 7] = cur7;
        if (l == 63) afin[512] = curT;
        const int end = 2 * Lb;
        const int em1 = (end > 0) ? end - 1 : 0;
        float ssum = afin[end] + afin[em1];     // same-wave DS, in-order
        ssum = fmaxf(ssum, 1e-37f);
        const float lnt = logf(ssum) + LN2_F * log2acc;

        WG_BARRIER;                        // accbuf ready (producers wrote)

        // lse sum in the OLD ctc_final order: q = 0..15 ascending
        float c = 0.f;
        #pragma unroll
        for (int q = 0; q < 16; ++q) c += accbuf[q];
        if (l == 0) vres[b] = c - lnt;
    } else {
        // ============================ producers ===========================
        const int s0   = wid - 1;          // slot 0..14
        const bool dual = (wid == 15);     // wave 15 also handles slot 15
        float accA = 0.f, accB = 0.f;

        float4 pc0{}, pn0{}, pc1{}, pn1{};
        if (NW > 0) {
            pc0 = *(const float4*)(lg + rs * (size_t)s0 + 4 * l);
            pn0 = *(const float4*)(lg + rs * (size_t)(16 + s0) + 4 * l);
            if (dual) {
                pc1 = *(const float4*)(lg + rs * (size_t)15 + 4 * l);
                pn1 = *(const float4*)(lg + rs * (size_t)31 + 4 * l);
            }
        }

        for (int k = 0; k <= NW; ++k) {
            if (k < NW) {
                const int hh = k & 1;
                const float4 x0 = pc0;
                pc0 = pn0;
                if (k + 2 < NW)
                    pn0 = *(const float4*)(lg + rs * (size_t)(16 * (k + 2) + s0) + 4 * l);
                float4 x1{};
                if (dual) {
                    x1 = pc1;
                    pc1 = pn1;
                    if (k + 2 < NW)
                        pn1 = *(const float4*)(lg + rs * (size_t)(16 * (k + 2) + 15) + 4 * l);
                }
                // stage exp'd rows (write-only; barrier orders visibility)
                float4 e0;
                e0.x = __expf(x0.x); e0.y = __expf(x0.y);
                e0.z = __expf(x0.z); e0.w = __expf(x0.w);
                *(float4*)&erow[hh][s0][4 * l] = e0;
                if (dual) {
                    float4 e1v;
                    e1v.x = __expf(x1.x); e1v.y = __expf(x1.y);
                    e1v.z = __expf(x1.z); e1v.w = __expf(x1.w);
                    *(float4*)&erow[hh][15][4 * l] = e1v;
                }
                // lse (identical ops/order as the old lse wave (b, q=s))
                {
                    float m = fmaxf(fmaxf(x0.x, x0.y), fmaxf(x0.z, x0.w));
                    m = wave_max_f(m);
                    float ss = __expf(x0.x - m) + __expf(x0.y - m) +
                               __expf(x0.z - m) + __expf(x0.w - m);
                    ss = wave_sum_f(ss);
                    const int t = 16 * k + s0;
                    if (t < Tb) accA += m + logf(ss);
                }
                if (dual) {
                    float m = fmaxf(fmaxf(x1.x, x1.y), fmaxf(x1.z, x1.w));
                    m = wave_max_f(m);
                    float ss = __expf(x1.x - m) + __expf(x1.y - m) +
                               __expf(x1.z - m) + __expf(x1.w - m);
                    ss = wave_sum_f(ss);
                    const int t = 16 * k + 15;
                    if (t < Tb) accB += m + logf(ss);
                }
            }
            WG_BARRIER;
        }

        // leftover lse rows (general Tb not multiple of 16; none at Tb=1024)
        for (int t = 16 * NW + s0; t < Tb; t += 16) {
            const float4 x = *(const float4*)(lg + rs * (size_t)t + 4 * l);
            float m = fmaxf(fmaxf(x.x, x.y), fmaxf(x.z, x.w));
            m = wave_max_f(m);
            float ss = __expf(x.x - m) + __expf(x.y - m) +
                       __expf(x.z - m) + __expf(x.w - m);
            ss = wave_sum_f(ss);
            accA += m + logf(ss);
        }
        if (dual) {
            for (int t = 16 * NW + 15; t < Tb; t += 16) {
                const float4 x = *(const float4*)(lg + rs * (size_t)t + 4 * l);
                float m = fmaxf(fmaxf(x.x, x.y), fmaxf(x.z, x.w));
                m = wave_max_f(m);
                float ss = __expf(x.x - m) + __expf(x.y - m) +
                           __expf(x.z - m) + __expf(x.w - m);
                ss = wave_sum_f(ss);
                accB += m + logf(ss);
            }
        }
        if (l == 0) {
            accbuf[s0] = accA;
            if (dual) accbuf[15] = accB;
        }
        WG_BARRIER;                        // publish accbuf to consumer
    }
}

__global__ __launch_bounds__(64) void ctc_final(
    const float* __restrict__ vres,        // [B]
    float* __restrict__ out, int B)
{
    const int b = threadIdx.x;
    float v = (b < B) ? vres[b] : 0.f;
    #pragma unroll
    for (int o = 32; o >= 1; o >>= 1) v += __shfl_xor(v, o, 64);
    if (threadIdx.x == 0) out[0] = v / (float)B;
}

// =====================================================================
// FALLBACK PATH (round-4 kernels, verbatim; FB_ macro names)
// =====================================================================
#define FB_PRE(N, S) do {                                              \
    G##N = *(const float4*)(&gbuf[h][S][l][0]);                        \
    A##N = bbuf[h][S];                                                 \
  } while (0)
#define FB_STEPR(N, S) do {                                            \
    MACS(A##N, G##N.x, G##N.y, G##N.z, G##N.w);                        \
    FB_PRE(N, S);                                                      \
  } while (0)
#define FB_STEPC(N) MACS(A##N, G##N.x, G##N.y, G##N.z, G##N.w)

#define FB_PLOAD(dst, WV, J)                                           \
    dst = *(const float4*)(lg + rs * (size_t)(16 * (WV) + p + 7 * (J)) + 4 * l)
#define FB_PROC(XV, i) do {                                            \
    float4 _e;                                                         \
    _e.x = __expf((XV).x); _e.y = __expf((XV).y);                      \
    _e.z = __expf((XV).z); _e.w = __expf((XV).w);                      \
    *(float4*)&prow[p][4 * l] = _e;                                    \
    const float* _pr = prow[p];                                        \
    float _gb = _pr[0];                                                \
    float4 _gv;                                                        \
    _gv.x = _pr[ix]; _gv.y = _pr[iy]; _gv.z = _pr[iz]; _gv.w = _pr[iw];\
    *(float4*)&gbuf[h][i][l][0] = _gv;                                 \
    if (l == 0) bbuf[h][i] = _gb;                                      \
  } while (0)

__global__ __launch_bounds__(512) void fb_ctc_main(
    const int*   __restrict__ labels,
    const float* __restrict__ logits,
    const int*   __restrict__ label_len,
    const int*   __restrict__ logit_len,
    float*       __restrict__ partial,
    float*       __restrict__ lnterm,
    int T, int B, int L)
{
    const int tid = threadIdx.x;
    const int wid = tid >> 6;
    const int l   = tid & 63;

    if ((int)blockIdx.x < B) {
        __shared__ __align__(16) float gbuf[2][16][64][4];
        __shared__ float bbuf[2][16];
        __shared__ __align__(16) float prow[7][256];
        __shared__ float afin[514];

        const int b = blockIdx.x;
        const int Tb = logit_len[b];
        const int Lb = label_len[b];
        const int Sb = 2 * Lb + 1;

        const float* lg = logits + (size_t)b * V;
        const size_t rs = (size_t)B * V;

        const int4 lb4 = ((const int4*)(labels + (size_t)b * L))[l];
        const int ix = lb4.x, iy = lb4.y, iz = lb4.z, iw = lb4.w;
        const int prevw = __shfl_up(iw, 1);
        const float sk1 = (l > 0 && ix != prevw) ? 1.f : 0.f;
        const float sk3 = (iy != ix) ? 1.f : 0.f;
        const float sk5 = (iz != iy) ? 1.f : 0.f;
        const float sk7 = (iw != iz) ? 1.f : 0.f;

        const float mk0 = (8 * l + 0 < Sb) ? 1.f : 0.f;
        const float mk1 = (8 * l + 1 < Sb) ? 1.f : 0.f;
        const float mk2 = (8 * l + 2 < Sb) ? 1.f : 0.f;
        const float mk3 = (8 * l + 3 < Sb) ? 1.f : 0.f;
        const float mk4 = (8 * l + 4 < Sb) ? 1.f : 0.f;
        const float mk5 = (8 * l + 5 < Sb) ? 1.f : 0.f;
        const float mk6 = (8 * l + 6 < Sb) ? 1.f : 0.f;
        const float mk7 = (8 * l + 7 < Sb) ? 1.f : 0.f;
        const float mkT = (Sb > 512 && l == 63) ? 1.f : 0.f;

        float cur0 = 0.f, cur1 = 0.f, cur2 = 0.f, cur3 = 0.f;
        float cur4 = 0.f, cur5 = 0.f, cur6 = 0.f, cur7 = 0.f, curT = 0.f;
        if (l == 0) {
            cur0 = __expf(lg[0]);
            cur1 = __expf(lg[ix]) * mk1;
        }
        float log2acc = 0.f;

        const int NW = Tb / 16;

        float4 G0{}, G1{}, G2{}, G3{}, G4{}, G5{}, G6{}, G7{};
        float  A0 = 0, A1 = 0, A2 = 0, A3 = 0, A4 = 0, A5 = 0, A6 = 0, A7 = 0;

        const int p = (wid > 0) ? wid - 1 : 0;
        const bool three = (p < 2);
        float4 ca{}, cb{}, cc{}, na{}, nb{}, nc{};
        if (wid > 0 && NW > 0) {
            FB_PLOAD(ca, 0, 0);
            FB_PLOAD(cb, 0, 1);
            if (three) FB_PLOAD(cc, 0, 2);
        }
        if (wid == 0) __builtin_amdgcn_s_setprio(1);

        for (int k = 0; k <= NW; ++k) {
            if (wid != 0) {
                if (k < NW) {
                    const int h = k & 1;
                    if (k + 1 < NW) {
                        FB_PLOAD(na, k + 1, 0);
                        FB_PLOAD(nb, k + 1, 1);
                        if (three) FB_PLOAD(nc, k + 1, 2);
                    }
                    FB_PROC(ca, p);
                    FB_PROC(cb, p + 7);
                    if (three) FB_PROC(cc, p + 14);
                    ca = na; cb = nb; cc = nc;
                }
            } else if (k >= 1) {
                const int w = k - 1;
                const int h = w & 1;
                if (w == 0) {
                    FB_PRE(1, 1); FB_PRE(2, 2); FB_PRE(3, 3); FB_PRE(4, 4);
                    FB_PRE(5, 5); FB_PRE(6, 6); FB_PRE(7, 7); FB_PRE(0, 8);
                    FB_STEPR(1, 9);  FB_STEPR(2, 10); FB_STEPR(3, 11);
                    FB_STEPR(4, 12); FB_STEPR(5, 13); FB_STEPR(6, 14);
                    FB_STEPR(7, 15);
                    FB_STEPC(0);
                    FB_STEPC(1); FB_STEPC(2); FB_STEPC(3); FB_STEPC(4);
                    FB_STEPC(5); FB_STEPC(6); FB_STEPC(7);
                } else {
                    FB_PRE(0, 0); FB_PRE(1, 1); FB_PRE(2, 2); FB_PRE(3, 3);
                    FB_PRE(4, 4); FB_PRE(5, 5); FB_PRE(6, 6); FB_PRE(7, 7);
                    FB_STEPR(0, 8);  FB_STEPR(1, 9);  FB_STEPR(2, 10);
                    FB_STEPR(3, 11); FB_STEPR(4, 12); FB_STEPR(5, 13);
                    FB_STEPR(6, 14); FB_STEPR(7, 15);
                    FB_STEPC(0); FB_STEPC(1); FB_STEPC(2); FB_STEPC(3);
                    FB_STEPC(4); FB_STEPC(5); FB_STEPC(6); FB_STEPC(7);
                }
                RENORM;
            }
            WG_BARRIER;
        }

        if (wid == 0) {
            for (int t = 16 * NW; t < Tb; ++t) {
                if (t < 1) continue;
                const float* rowp = lg + rs * (size_t)t;
                const float eb = __expf(rowp[0]);
                const float e1 = __expf(rowp[ix]), e3 = __expf(rowp[iy]);
                const float e5 = __expf(rowp[iz]), e7 = __expf(rowp[iw]);
                MACS(eb, e1, e3, e5, e7);
            }

            afin[8 * l + 0] = cur0; afin[8 * l + 1] = cur1;
            afin[8 * l + 2] = cur2; afin[8 * l + 3] = cur3;
            afin[8 * l + 4] = cur4; afin[8 * l + 5] = cur5;
            afin[8 * l + 6] = cur6; afin[8 * l + 7] = cur7;
            if (l == 63) afin[512] = curT;
            const int end = 2 * Lb;
            const int em1 = (end > 0) ? end - 1 : 0;
            float ssum = afin[end] + afin[em1];
            ssum = fmaxf(ssum, 1e-37f);
            if (l == 0) lnterm[b] = logf(ssum) + LN2_F * log2acc;
        }
    } else {
        const int w  = ((int)blockIdx.x - B) * 8 + wid;
        const int nW = ((int)gridDim.x - B) * 8;
        const int rows = T * B;
        const int bb = w % B;
        const int Tbb = logit_len[bb];
        float acc = 0.f;
        int r = w;
        if (r < rows) {
            int t = w / B;
            const int ts = nW / B;
            float4 nxt = ((const float4*)(logits + (size_t)r * V))[l];
            while (true) {
                const int rn = r + nW;
                const bool more = rn < rows;
                const float4 x = nxt;
                if (more) nxt = ((const float4*)(logits + (size_t)rn * V))[l];
                float m = fmaxf(fmaxf(x.x, x.y), fmaxf(x.z, x.w));
                m = wave_max_f(m);
                float ss = __expf(x.x - m) + __expf(x.y - m) +
                           __expf(x.z - m) + __expf(x.w - m);
                ss = wave_sum_f(ss);
                if (t < Tbb) acc += m + logf(ss);
                if (!more) break;
                r = rn; t += ts;
            }
        }
        if (l == 0) partial[w] = acc;
    }
}

__global__ __launch_bounds__(64) void fb_ctc_final(
    const float* __restrict__ partial,
    const float* __restrict__ lnterm,
    float* __restrict__ out, int B, int nW)
{
    const int b = threadIdx.x;
    float v = 0.f;
    if (b < B) {
        float c = 0.f;
        for (int k = b; k < nW; k += B) c += partial[k];
        v = c - lnterm[b];
    }
    #pragma unroll
    for (int o = 32; o >= 1; o >>= 1) v += __shfl_xor(v, o, 64);
    if (threadIdx.x == 0) out[0] = v / (float)B;
}

extern "C" void kernel_launch(void* const* d_in, const int* in_sizes, int n_in,
                              void* d_out, int out_size, void* d_ws, size_t ws_size,
                              hipStream_t stream) {
    const int*   labels    = (const int*)d_in[0];
    const float* logits    = (const float*)d_in[1];
    const int*   label_len = (const int*)d_in[2];
    const int*   logit_len = (const int*)d_in[3];

    const int B = in_sizes[2];                 // 64
    const int L = in_sizes[0] / B;             // 256
    const int T = in_sizes[1] / (B * V);       // 1024

    if (T == 1024 && B == 64 && L == 256 && ws_size >= (size_t)B * sizeof(float)) {
        float* vres = (float*)d_ws;            // [B]
        ctc_main<<<B, 1024, 0, stream>>>(labels, logits, label_len, logit_len,
                                         vres, T, B, L);
        ctc_final<<<1, 64, 0, stream>>>(vres, (float*)d_out, B);
    } else {
        const int nLse = 1024;
        float* partial = (float*)d_ws;         // [nLse]
        float* lnterm  = partial + nLse;       // [B]
        fb_ctc_main<<<B + nLse / 8, 512, 0, stream>>>(labels, logits,
                                                      label_len, logit_len,
                                                      partial, lnterm,
                                                      T, B, L);
        fb_ctc_final<<<1, 64, 0, stream>>>(partial, lnterm, (float*)d_out,
                                           B, nLse);
    }
}